// Round 4
// baseline (269.857 us; speedup 1.0000x reference)
//
#include <hip/hip_runtime.h>

// TaylorFeatureMap: x (2,16,2048,64) fp32 -> out (2,16,2048,2145) fp32
// Row layout per vector v:
//   [0]        = 1
//   [1..64]    = x[i] / 64^0.25
//   [65..128]  = x[i]^2 / (8*sqrt(2))
//   [129..2144]= x[i]*x[j] / 8, (i,j) = triu_indices(64, k=1) row-major
//
// R3 structure: 4 waves/block, one row per wave, 16 row-groups per block
// (1024 blocks = 4 resident/CU). Per group: compute row into LDS
// (readlane broadcast + masked contiguous ds_write), barrier, LDS->regs
// (9 float4/thread), barrier, regs->global dense aligned dwordx4.
// Barriers are raw `s_waitcnt lgkmcnt(0); s_barrier` — they NEVER drain
// vmcnt, so global stores from group g stay in flight under group g+1's
// compute (hipcc's __syncthreads would insert vmcnt(0) and serialize the
// store stream — the R2 bottleneck). x for g+1 is prefetched BEFORE the
// stores so (in-order vmcnt retirement) its use never drains the stores.

#define D 64
#define ROW 2145
#define OFFD_BASE 129
#define RPB 4                       // rows per block (= waves)
#define GROUPS 16                   // row-groups per block
#define NF4 (RPB * ROW / 4)         // 2145 float4 per group

// LDS-only barrier: waits own ds ops, never vmcnt. "memory" clobber keeps
// the compiler from moving LDS/global ops across it.
#define BAR_LGKM() asm volatile("s_waitcnt lgkmcnt(0)\n\ts_barrier" ::: "memory")

__global__ __launch_bounds__(256) void taylor_fm_kernel(
    const float* __restrict__ x, float* __restrict__ out) {
    __shared__ __align__(16) float buf[RPB * ROW];   // 34,320 B

    const int wave = threadIdx.x >> 6;
    const int lane = threadIdx.x & 63;

    const float inv_rrd   = 0.35355339059327373f;   // 1/64^0.25
    const float inv_rd_r2 = 0.08838834764831845f;   // 1/(8*sqrt(2))

    float* brow = buf + wave * ROW;
    float* tri  = brow + OFFD_BASE;
    const float4* b4 = reinterpret_cast<const float4*>(buf);

    int grp = blockIdx.x * GROUPS;
    float xl = x[((size_t)grp * RPB + wave) * D + lane];

    for (int g = 0; g < GROUPS; ++g, ++grp) {
        // ---- phase 1: compute this row into LDS ----
        if (lane == 0) brow[0] = 1.0f;
        brow[1 + lane]  = xl * inv_rrd;
        brow[65 + lane] = xl * xl * inv_rd_r2;
        // exact pow2 pre-scale: (x_i/8)*x_j == (x_i*x_j)/8 bit-exactly
        const float xls = xl * 0.125f;
#pragma unroll
        for (int i = 0; i < 63; ++i) {
            const int Ci = (i * (127 - i)) >> 1;    // segment start of row i
            float xi = __uint_as_float(
                __builtin_amdgcn_readlane(__float_as_uint(xls), i));
            if (lane > i) {
                tri[Ci - i - 1 + lane] = xi * xl;
            }
        }
        BAR_LGKM();                                 // writes visible to block

        // ---- prefetch next group's x (before stores: in-order vmcnt) ----
        float xl_next = xl;
        if (g + 1 < GROUPS) {
            xl_next = x[((size_t)(grp + 1) * RPB + wave) * D + lane];
        }

        // ---- phase 2a: LDS -> regs (9 float4 per thread) ----
        float4 r[9];
        int q = threadIdx.x;
#pragma unroll
        for (int k = 0; k < 8; ++k, q += 256) r[k] = b4[q];
        const bool tail = (q < NF4);                // 2145 - 8*256 = 97
        if (tail) r[8] = b4[q];
        BAR_LGKM();                                 // reads in regs; LDS free

        // ---- phase 2b: regs -> global, dense aligned dwordx4 ----
        float4* o4 = reinterpret_cast<float4*>(out + (size_t)grp * (RPB * ROW));
        q = threadIdx.x;
#pragma unroll
        for (int k = 0; k < 8; ++k, q += 256) o4[q] = r[k];
        if (tail) o4[q] = r[8];

        xl = xl_next;
    }
}

extern "C" void kernel_launch(void* const* d_in, const int* in_sizes, int n_in,
                              void* d_out, int out_size, void* d_ws, size_t ws_size,
                              hipStream_t stream) {
    const float* x = (const float*)d_in[0];
    float* out = (float*)d_out;
    int nrows = in_sizes[0] / D;                    // 65536
    int nblocks = nrows / (RPB * GROUPS);           // 1024
    taylor_fm_kernel<<<nblocks, 256, 0, stream>>>(x, out);
}

// Round 5
// 123.012 us; speedup vs baseline: 2.1937x; 2.1937x over previous
//
#include <hip/hip_runtime.h>

// TaylorFeatureMap: x (2,16,2048,64) fp32 -> out (2,16,2048,2145) fp32
// Row layout per vector v:
//   [0]        = 1
//   [1..64]    = x[i] / 64^0.25
//   [65..128]  = x[i]^2 / (8*sqrt(2))
//   [129..2144]= x[i]*x[j] / 8, (i,j) = triu_indices(64, k=1) row-major
//
// R4: revert to the known-good R2 structure (compute row into LDS via
// readlane-broadcast + masked contiguous ds_write; one __syncthreads; dense
// aligned vector stores), but shrink the block: RPB=2 rows / 128 threads /
// 17,160 B LDS -> 9 resident blocks per CU (vs 4 with RPB=4). More,
// smaller, mutually desynchronized blocks keep the store stream full across
// phase-1 compute bubbles and block-launch latency (the R2 gap: 5.1 vs
// 6.6 TB/s). Block chunk = 17,160 B = 2145 float2, 8B-aligned -> dense
// dwordx2 stores (8 B/lane sweet spot). NO inline-asm barriers (R3 lesson:
// 2.4x regression). The single __syncthreads' vmcnt drain is free: the only
// prior VMEM op (x load) is already consumed.

#define D 64
#define ROW 2145
#define OFFD_BASE 129
#define RPB 2                       // rows per block (= waves per block)
#define NF2 (RPB * ROW / 2)         // 2145 float2 per block

__global__ __launch_bounds__(128) void taylor_fm_kernel(
    const float* __restrict__ x, float* __restrict__ out) {
    __shared__ __align__(16) float buf[RPB * ROW];   // 17,160 B

    const int wave = threadIdx.x >> 6;
    const int lane = threadIdx.x & 63;
    const int row  = blockIdx.x * RPB + wave;

    const float xl = x[(size_t)row * D + lane];

    const float inv_rrd   = 0.35355339059327373f;   // 1/64^0.25
    const float inv_rd_r2 = 0.08838834764831845f;   // 1/(8*sqrt(2))

    float* brow = buf + wave * ROW;
    if (lane == 0) brow[0] = 1.0f;
    brow[1 + lane]  = xl * inv_rrd;
    brow[65 + lane] = xl * xl * inv_rd_r2;

    // Pre-scale by exact pow2 1/8 so (x_i/8)*x_j == (x_i*x_j)/8 bit-exactly.
    const float xls = xl * 0.125f;

    float* tri = brow + OFFD_BASE;
#pragma unroll
    for (int i = 0; i < 63; ++i) {
        const int Ci = (i * (127 - i)) >> 1;        // start of row i's segment
        float xi = __uint_as_float(
            __builtin_amdgcn_readlane(__float_as_uint(xls), i));
        if (lane > i) {
            tri[Ci - i - 1 + lane] = xi * xl;
        }
    }

    __syncthreads();

    // Dense aligned float2 stream: 2145 float2 per block.
    const float2* b2 = reinterpret_cast<const float2*>(buf);
    float2* o2 = reinterpret_cast<float2*>(out + (size_t)blockIdx.x * (RPB * ROW));
    int q = threadIdx.x;
#pragma unroll
    for (int k = 0; k < 16; ++k, q += 128) {
        o2[q] = b2[q];
    }
    if (q < NF2) {                  // tail: 2145 - 16*128 = 97 float2
        o2[q] = b2[q];
    }
}

extern "C" void kernel_launch(void* const* d_in, const int* in_sizes, int n_in,
                              void* d_out, int out_size, void* d_ws, size_t ws_size,
                              hipStream_t stream) {
    const float* x = (const float*)d_in[0];
    float* out = (float*)d_out;
    int nrows = in_sizes[0] / D;        // 65536
    taylor_fm_kernel<<<nrows / RPB, 128, 0, stream>>>(x, out);
}